// Round 1
// baseline (246.303 us; speedup 1.0000x reference)
//
#include <hip/hip_runtime.h>
#include <hip/hip_bf16.h>

// B=8, N=4096, C=384, H=8, HD=48.  M = B*N = 32768.
// qkv GEMM: (32768x384) x (1152x384)^T -> 32768x1152
// proj GEMM: (32768x384) x (384x384)^T -> 32768x384

typedef __attribute__((ext_vector_type(8))) short short8;
typedef __attribute__((ext_vector_type(4))) float floatx4;

#define MFMA(a, b, c) __builtin_amdgcn_mfma_f32_16x16x32_bf16((a), (b), (c), 0, 0, 0)

__device__ __forceinline__ unsigned short f2bf(float f) {
  union { float f; unsigned u; } x; x.f = f;
  unsigned r = x.u + 0x7FFFu + ((x.u >> 16) & 1u);   // RNE
  return (unsigned short)(r >> 16);
}

// ---------------- fp32 -> bf16 convert (n % 4 == 0) ----------------
__global__ void convf2b(const float* __restrict__ in, unsigned short* __restrict__ out, int n) {
  int stride = gridDim.x * blockDim.x * 4;
  for (int i = (blockIdx.x * blockDim.x + threadIdx.x) * 4; i < n; i += stride) {
    float4 v = *(const float4*)(in + i);
    uint2 o;
    o.x = (unsigned)f2bf(v.x) | ((unsigned)f2bf(v.y) << 16);
    o.y = (unsigned)f2bf(v.z) | ((unsigned)f2bf(v.w) << 16);
    *(uint2*)(out + i) = o;
  }
}

// ---------------- 128x128 MFMA GEMM, Bt input (N x K row-major) ----------------
// EPI 0: qkv epilogue -> bf16, relu(dn*v)+1e-3 for cols < 768
// EPI 1: proj epilogue -> fp32, + bias
template <int EPI>
__global__ __launch_bounds__(256, 2) void gemm_bt(
    const unsigned short* __restrict__ A,   // M x K bf16
    const unsigned short* __restrict__ Bt,  // N x K bf16
    void* __restrict__ Cout,
    const float* __restrict__ bias,
    int M, int N, int K, int ldc) {
  __shared__ unsigned short As[128 * 64];
  __shared__ unsigned short Bs[128 * 64];
  const int NT = N >> 7;
  const int bid = blockIdx.x;
  const int bn = bid % NT;
  const int bm = bid / NT;
  const int tid = threadIdx.x;
  const int w = tid >> 6, lane = tid & 63;
  const int wm = w >> 1, wn = w & 1;
  const int l15 = lane & 15, l4 = lane >> 4;

  floatx4 zero = {0.f, 0.f, 0.f, 0.f};
  floatx4 acc[4][4];
#pragma unroll
  for (int i = 0; i < 4; ++i)
#pragma unroll
    for (int j = 0; j < 4; ++j) acc[i][j] = zero;

  const int li0 = (w * 4) * 64 + lane;
  const size_t Abase = (size_t)(bm * 128) * K;
  const size_t Bbase = (size_t)(bn * 128) * K;

  for (int k0 = 0; k0 < K; k0 += 64) {
#pragma unroll
    for (int i = 0; i < 4; ++i) {
      int li = li0 + i * 64;
      int row = li >> 3;
      int col = (li & 7) << 3;
      const unsigned short* gA = A + Abase + (size_t)row * K + k0 + col;
      const unsigned short* gB = Bt + Bbase + (size_t)row * K + k0 + col;
      __builtin_amdgcn_global_load_lds((const __attribute__((address_space(1))) void*)gA,
                                       (__attribute__((address_space(3))) void*)&As[(w * 4 + i) * 512],
                                       16, 0, 0);
      __builtin_amdgcn_global_load_lds((const __attribute__((address_space(1))) void*)gB,
                                       (__attribute__((address_space(3))) void*)&Bs[(w * 4 + i) * 512],
                                       16, 0, 0);
    }
    __syncthreads();
#pragma unroll
    for (int kk = 0; kk < 2; ++kk) {
      short8 a[4], b[4];
#pragma unroll
      for (int mf = 0; mf < 4; ++mf)
        a[mf] = *(const short8*)&As[(wm * 64 + mf * 16 + l15) * 64 + kk * 32 + l4 * 8];
#pragma unroll
      for (int nf = 0; nf < 4; ++nf)
        b[nf] = *(const short8*)&Bs[(wn * 64 + nf * 16 + l15) * 64 + kk * 32 + l4 * 8];
#pragma unroll
      for (int mf = 0; mf < 4; ++mf)
#pragma unroll
        for (int nf = 0; nf < 4; ++nf)
          acc[mf][nf] = MFMA(a[mf], b[nf], acc[mf][nf]);
    }
    __syncthreads();
  }

  const float DN = 0.3799178430f;  // 48^-0.25
#pragma unroll
  for (int mf = 0; mf < 4; ++mf) {
#pragma unroll
    for (int nf = 0; nf < 4; ++nf) {
      int gm0 = bm * 128 + wm * 64 + mf * 16 + l4 * 4;
      int gn = bn * 128 + wn * 64 + nf * 16 + l15;
#pragma unroll
      for (int r = 0; r < 4; ++r) {
        float v = acc[mf][nf][r];
        size_t off = (size_t)(gm0 + r) * ldc + gn;
        if (EPI == 0) {
          if (gn < 768) v = fmaxf(v * DN, 0.f) + 1e-3f;
          ((unsigned short*)Cout)[off] = f2bf(v);
        } else {
          ((float*)Cout)[off] = v + bias[gn];
        }
      }
    }
  }
}

// ---------------- kptv[d][m] = sum_n v[n,d]*kp[n,m]; row 48 = ks[m] ----------------
// grid = 64 bh * 8 token-groups; fp32 atomic accumulate into accD[bh][64][48]
__global__ __launch_bounds__(256, 2) void attn_ksum(
    const unsigned short* __restrict__ qkv,  // (B*4096) x 1152 bf16 (post-activation)
    float* __restrict__ accD) {
  const int bh = blockIdx.x >> 3, g = blockIdx.x & 7;
  const int b = bh >> 3, h = bh & 7;
  const int tid = threadIdx.x, w = tid >> 6, lane = tid & 63;
  const int l15 = lane & 15, l4 = lane >> 4;
  __shared__ unsigned short Kpt[48 * 136];
  __shared__ unsigned short Vt[48 * 136];
  __shared__ float red[64 * 48];

  floatx4 zero = {0.f, 0.f, 0.f, 0.f};
  floatx4 acc[4][3];
#pragma unroll
  for (int i = 0; i < 4; ++i)
#pragma unroll
    for (int j = 0; j < 3; ++j) acc[i][j] = zero;

  unsigned short ov = (l15 == 0) ? (unsigned short)0x3F80 : (unsigned short)0;
  short8 ones;
#pragma unroll
  for (int e = 0; e < 8; ++e) ones[e] = (short)ov;

  const size_t rowbase = (size_t)b * 4096;
  const int t = tid >> 1, hf = tid & 1;

  for (int c = 0; c < 4; ++c) {
    int tok0 = g * 512 + c * 128;
    const unsigned short* kr = qkv + (rowbase + tok0 + t) * 1152 + 384 + h * 48 + hf * 24;
    const unsigned short* vr = kr + 384;
#pragma unroll
    for (int j = 0; j < 3; ++j) {
      short8 kv = *(const short8*)(kr + j * 8);
      short8 vv = *(const short8*)(vr + j * 8);
#pragma unroll
      for (int e = 0; e < 8; ++e) {
        int m = hf * 24 + j * 8 + e;
        Kpt[m * 136 + t] = (unsigned short)kv[e];
        Vt[m * 136 + t] = (unsigned short)vv[e];
      }
    }
    __syncthreads();
    {
      int col = w * 32 + l4 * 8;
      short8 a[3], bb[3];
#pragma unroll
      for (int f = 0; f < 3; ++f) {
        a[f] = *(const short8*)&Vt[(f * 16 + l15) * 136 + col];
        bb[f] = *(const short8*)&Kpt[(f * 16 + l15) * 136 + col];
      }
#pragma unroll
      for (int af = 0; af < 3; ++af)
#pragma unroll
        for (int bf = 0; bf < 3; ++bf)
          acc[af][bf] = MFMA(a[af], bb[bf], acc[af][bf]);
#pragma unroll
      for (int bf = 0; bf < 3; ++bf)
        acc[3][bf] = MFMA(ones, bb[bf], acc[3][bf]);
    }
    __syncthreads();
  }

  for (int i = tid; i < 64 * 48; i += 256) red[i] = 0.f;
  __syncthreads();
#pragma unroll
  for (int af = 0; af < 4; ++af)
#pragma unroll
    for (int bf = 0; bf < 3; ++bf)
#pragma unroll
      for (int r = 0; r < 4; ++r)
        atomicAdd(&red[(af * 16 + l4 * 4 + r) * 48 + bf * 16 + l15], acc[af][bf][r]);
  __syncthreads();
  float* dst = accD + (size_t)bh * 64 * 48;
  for (int i = tid; i < 64 * 48; i += 256) atomicAdd(&dst[i], red[i]);
}

// ---------------- accD fp32 [bh][64][48] -> kptv bf16 [bh][64][64] (zero padded) ----------------
__global__ void fixup_kptv(const float* __restrict__ accD, unsigned short* __restrict__ kptv) {
  int bh = blockIdx.x, tid = threadIdx.x;
  for (int i = tid; i < 64 * 64; i += 256) {
    int r = i >> 6, c = i & 63;
    float v = (c < 48) ? accD[(size_t)bh * 3072 + r * 48 + c] : 0.f;
    kptv[(size_t)bh * 4096 + i] = f2bf(v);
  }
}

// ---------------- out[n,d] = (qp[n,:] . kptv[d,:]) / (qp[n,:] . ks + eps) ----------------
// written in scrambled layout: outr[b, h*512 + n/8, (n%8)*48 + d]
__global__ __launch_bounds__(256, 2) void attn_out(
    const unsigned short* __restrict__ qkv,
    const unsigned short* __restrict__ kptv,
    unsigned short* __restrict__ outr) {
  const int bh = blockIdx.x >> 4, tg = blockIdx.x & 15;
  const int b = bh >> 3, h = bh & 7;
  const int tid = threadIdx.x, w = tid >> 6, lane = tid & 63;
  const int l15 = lane & 15, l4 = lane >> 4;
  const int t0 = tg * 256 + w * 64;

  short8 bfr[2][4];
#pragma unroll
  for (int kk = 0; kk < 2; ++kk)
#pragma unroll
    for (int nf = 0; nf < 4; ++nf)
      bfr[kk][nf] = *(const short8*)&kptv[(size_t)bh * 4096 + (nf * 16 + l15) * 64 + kk * 32 + l4 * 8];

  floatx4 zero = {0.f, 0.f, 0.f, 0.f};
  floatx4 acc[4][4];
#pragma unroll
  for (int i = 0; i < 4; ++i)
#pragma unroll
    for (int j = 0; j < 4; ++j) acc[i][j] = zero;

  const size_t rb = (size_t)b * 4096;
#pragma unroll
  for (int mf = 0; mf < 4; ++mf) {
#pragma unroll
    for (int kk = 0; kk < 2; ++kk) {
      int tt = t0 + mf * 16 + l15;
      short8 a = *(const short8*)&qkv[(rb + tt) * 1152 + h * 48 + kk * 32 + l4 * 8];
#pragma unroll
      for (int nf = 0; nf < 4; ++nf)
        acc[mf][nf] = MFMA(a, bfr[kk][nf], acc[mf][nf]);
    }
  }

#pragma unroll
  for (int mf = 0; mf < 4; ++mf) {
    float den[4];
#pragma unroll
    for (int r = 0; r < 4; ++r)
      den[r] = __shfl(acc[mf][3][r], lane & 48, 64) + 1e-8f;
#pragma unroll
    for (int nf = 0; nf < 3; ++nf) {
#pragma unroll
      for (int r = 0; r < 4; ++r) {
        int tt = t0 + mf * 16 + l4 * 4 + r;
        int d = nf * 16 + l15;
        float v = acc[mf][nf][r] / den[r];
        int np = h * 512 + (tt >> 3);
        int cp = (tt & 7) * 48 + d;
        outr[(rb + np) * 384 + cp] = f2bf(v);
      }
    }
  }
}

extern "C" void kernel_launch(void* const* d_in, const int* in_sizes, int n_in,
                              void* d_out, int out_size, void* d_ws, size_t ws_size,
                              hipStream_t stream) {
  const float* x = (const float*)d_in[0];
  const float* Wqkv = (const float*)d_in[1];
  const float* Wproj = (const float*)d_in[2];
  const float* bproj = (const float*)d_in[3];

  char* ws = (char*)d_ws;
  unsigned short* xb = (unsigned short*)(ws);                 // 32768*384*2      = 25165824
  unsigned short* wqkvb = (unsigned short*)(ws + 25165824);   // 1152*384*2       = 884736
  unsigned short* wprojb = (unsigned short*)(ws + 26050560);  // 384*384*2        = 294912
  unsigned short* qkvA = (unsigned short*)(ws + 26345472);    // 32768*1152*2     = 75497472
  float* accD = (float*)(ws + 101842944);                     // 64*64*48*4       = 786432
  unsigned short* kptv = (unsigned short*)(ws + 102629376);   // 64*64*64*2       = 524288
  unsigned short* outr = (unsigned short*)(ws + 103153664);   // 32768*384*2      = 25165824
  // total ws use: 128319488 bytes

  convf2b<<<2048, 256, 0, stream>>>(x, xb, 32768 * 384);
  convf2b<<<432, 256, 0, stream>>>(Wqkv, wqkvb, 1152 * 384);
  convf2b<<<144, 256, 0, stream>>>(Wproj, wprojb, 384 * 384);
  hipMemsetAsync(accD, 0, 786432, stream);

  gemm_bt<0><<<2304, 256, 0, stream>>>(xb, wqkvb, (void*)qkvA, nullptr, 32768, 1152, 384, 1152);
  attn_ksum<<<512, 256, 0, stream>>>(qkvA, accD);
  fixup_kptv<<<64, 256, 0, stream>>>(accD, kptv);
  attn_out<<<1024, 256, 0, stream>>>(qkvA, kptv, outr);
  gemm_bt<1><<<768, 256, 0, stream>>>(outr, wprojb, d_out, bproj, 32768, 384, 384, 384);
}

// Round 2
// 217.707 us; speedup vs baseline: 1.1313x; 1.1313x over previous
//
#include <hip/hip_runtime.h>
#include <hip/hip_bf16.h>

// B=8, N=4096, C=384, H=8, HD=48.  M = B*N = 32768.
// qkv GEMM: (32768x384) x (1152x384)^T -> 32768x1152
// proj GEMM: (32768x384) x (384x384)^T -> 32768x384

typedef __attribute__((ext_vector_type(8))) short short8;
typedef __attribute__((ext_vector_type(4))) float floatx4;

#define MFMA(a, b, c) __builtin_amdgcn_mfma_f32_16x16x32_bf16((a), (b), (c), 0, 0, 0)

__device__ __forceinline__ unsigned short f2bf(float f) {
  union { float f; unsigned u; } x; x.f = f;
  unsigned r = x.u + 0x7FFFu + ((x.u >> 16) & 1u);   // RNE
  return (unsigned short)(r >> 16);
}

__device__ __forceinline__ void cv4(const float* __restrict__ in, unsigned short* __restrict__ out, int i) {
  float4 v = *(const float4*)(in + i);
  uint2 o;
  o.x = (unsigned)f2bf(v.x) | ((unsigned)f2bf(v.y) << 16);
  o.y = (unsigned)f2bf(v.z) | ((unsigned)f2bf(v.w) << 16);
  *(uint2*)(out + i) = o;
}

// ---------------- all fp32 -> bf16 conversions + accD zeroing, one launch ----------------
__global__ void conv_all(const float* __restrict__ x, const float* __restrict__ wq,
                         const float* __restrict__ wp,
                         unsigned short* __restrict__ xb, unsigned short* __restrict__ wqb,
                         unsigned short* __restrict__ wpb, float* __restrict__ accD) {
  const int tid = blockIdx.x * blockDim.x + threadIdx.x;
  const int stride = gridDim.x * blockDim.x * 4;
  for (int i = tid * 4; i < 12582912; i += stride) cv4(x, xb, i);
  for (int i = tid * 4; i < 442368; i += stride) cv4(wq, wqb, i);
  for (int i = tid * 4; i < 147456; i += stride) cv4(wp, wpb, i);
  float4 z = {0.f, 0.f, 0.f, 0.f};
  for (int i = tid * 4; i < 196608; i += stride) *(float4*)(accD + i) = z;
}

// ---------------- 128x128 MFMA GEMM, Bt input (N x K row-major) ----------------
// EPI 0: qkv epilogue -> bf16, relu(dn*v)+1e-3 for cols < 768
// EPI 1: proj epilogue -> fp32, + bias
// XCD-aware bijective swizzle (grid % 8 == 0): consecutive tiles -> same XCD L2.
template <int EPI>
__global__ __launch_bounds__(256, 2) void gemm_bt(
    const unsigned short* __restrict__ A,   // M x K bf16
    const unsigned short* __restrict__ Bt,  // N x K bf16
    void* __restrict__ Cout,
    const float* __restrict__ bias,
    int M, int N, int K, int ldc) {
  __shared__ unsigned short As[128 * 64];
  __shared__ unsigned short Bs[128 * 64];
  const int NT = N >> 7;
  const int cpx = gridDim.x >> 3;
  const int bid = (blockIdx.x & 7) * cpx + (blockIdx.x >> 3);
  const int bn = bid % NT;
  const int bm = bid / NT;
  const int tid = threadIdx.x;
  const int w = tid >> 6, lane = tid & 63;
  const int wm = w >> 1, wn = w & 1;
  const int l15 = lane & 15, l4 = lane >> 4;

  floatx4 zero = {0.f, 0.f, 0.f, 0.f};
  floatx4 acc[4][4];
#pragma unroll
  for (int i = 0; i < 4; ++i)
#pragma unroll
    for (int j = 0; j < 4; ++j) acc[i][j] = zero;

  const int li0 = (w * 4) * 64 + lane;
  const size_t Abase = (size_t)(bm * 128) * K;
  const size_t Bbase = (size_t)(bn * 128) * K;

  for (int k0 = 0; k0 < K; k0 += 64) {
#pragma unroll
    for (int i = 0; i < 4; ++i) {
      int li = li0 + i * 64;
      int row = li >> 3;
      int col = (li & 7) << 3;
      const unsigned short* gA = A + Abase + (size_t)row * K + k0 + col;
      const unsigned short* gB = Bt + Bbase + (size_t)row * K + k0 + col;
      __builtin_amdgcn_global_load_lds((const __attribute__((address_space(1))) void*)gA,
                                       (__attribute__((address_space(3))) void*)&As[(w * 4 + i) * 512],
                                       16, 0, 0);
      __builtin_amdgcn_global_load_lds((const __attribute__((address_space(1))) void*)gB,
                                       (__attribute__((address_space(3))) void*)&Bs[(w * 4 + i) * 512],
                                       16, 0, 0);
    }
    __syncthreads();
#pragma unroll
    for (int kk = 0; kk < 2; ++kk) {
      short8 a[4], b[4];
#pragma unroll
      for (int mf = 0; mf < 4; ++mf)
        a[mf] = *(const short8*)&As[(wm * 64 + mf * 16 + l15) * 64 + kk * 32 + l4 * 8];
#pragma unroll
      for (int nf = 0; nf < 4; ++nf)
        b[nf] = *(const short8*)&Bs[(wn * 64 + nf * 16 + l15) * 64 + kk * 32 + l4 * 8];
#pragma unroll
      for (int mf = 0; mf < 4; ++mf)
#pragma unroll
        for (int nf = 0; nf < 4; ++nf)
          acc[mf][nf] = MFMA(a[mf], b[nf], acc[mf][nf]);
    }
    __syncthreads();
  }

  const float DN = 0.3799178430f;  // 48^-0.25
#pragma unroll
  for (int mf = 0; mf < 4; ++mf) {
#pragma unroll
    for (int nf = 0; nf < 4; ++nf) {
      int gm0 = bm * 128 + wm * 64 + mf * 16 + l4 * 4;
      int gn = bn * 128 + wn * 64 + nf * 16 + l15;
#pragma unroll
      for (int r = 0; r < 4; ++r) {
        float v = acc[mf][nf][r];
        size_t off = (size_t)(gm0 + r) * ldc + gn;
        if (EPI == 0) {
          if (gn < 768) v = fmaxf(v * DN, 0.f) + 1e-3f;
          ((unsigned short*)Cout)[off] = f2bf(v);
        } else {
          ((float*)Cout)[off] = v + bias[gn];
        }
      }
    }
  }
}

// ---------------- kptv[d][m] = sum_n v[n,d]*kp[n,m]; row 48 = ks[m] ----------------
// grid = 64 bh * 8 token-groups; fp32 atomic accumulate into accD[bh][64][48]
__global__ __launch_bounds__(256, 2) void attn_ksum(
    const unsigned short* __restrict__ qkv,  // (B*4096) x 1152 bf16 (post-activation)
    float* __restrict__ accD) {
  const int bh = blockIdx.x >> 3, g = blockIdx.x & 7;
  const int b = bh >> 3, h = bh & 7;
  const int tid = threadIdx.x, w = tid >> 6, lane = tid & 63;
  const int l15 = lane & 15, l4 = lane >> 4;
  __shared__ unsigned short Kpt[48 * 136];
  __shared__ unsigned short Vt[48 * 136];
  __shared__ float red[64 * 48];

  floatx4 zero = {0.f, 0.f, 0.f, 0.f};
  floatx4 acc[4][3];
#pragma unroll
  for (int i = 0; i < 4; ++i)
#pragma unroll
    for (int j = 0; j < 3; ++j) acc[i][j] = zero;

  unsigned short ov = (l15 == 0) ? (unsigned short)0x3F80 : (unsigned short)0;
  short8 ones;
#pragma unroll
  for (int e = 0; e < 8; ++e) ones[e] = (short)ov;

  const size_t rowbase = (size_t)b * 4096;
  const int t = tid >> 1, hf = tid & 1;

  for (int c = 0; c < 4; ++c) {
    int tok0 = g * 512 + c * 128;
    const unsigned short* kr = qkv + (rowbase + tok0 + t) * 1152 + 384 + h * 48 + hf * 24;
    const unsigned short* vr = kr + 384;
#pragma unroll
    for (int j = 0; j < 3; ++j) {
      short8 kv = *(const short8*)(kr + j * 8);
      short8 vv = *(const short8*)(vr + j * 8);
#pragma unroll
      for (int e = 0; e < 8; ++e) {
        int m = hf * 24 + j * 8 + e;
        Kpt[m * 136 + t] = (unsigned short)kv[e];
        Vt[m * 136 + t] = (unsigned short)vv[e];
      }
    }
    __syncthreads();
    {
      int col = w * 32 + l4 * 8;
      short8 a[3], bb[3];
#pragma unroll
      for (int f = 0; f < 3; ++f) {
        a[f] = *(const short8*)&Vt[(f * 16 + l15) * 136 + col];
        bb[f] = *(const short8*)&Kpt[(f * 16 + l15) * 136 + col];
      }
#pragma unroll
      for (int af = 0; af < 3; ++af)
#pragma unroll
        for (int bf = 0; bf < 3; ++bf)
          acc[af][bf] = MFMA(a[af], bb[bf], acc[af][bf]);
#pragma unroll
      for (int bf = 0; bf < 3; ++bf)
        acc[3][bf] = MFMA(ones, bb[bf], acc[3][bf]);
    }
    __syncthreads();
  }

  for (int i = tid; i < 64 * 48; i += 256) red[i] = 0.f;
  __syncthreads();
#pragma unroll
  for (int af = 0; af < 4; ++af)
#pragma unroll
    for (int bf = 0; bf < 3; ++bf)
#pragma unroll
      for (int r = 0; r < 4; ++r)
        atomicAdd(&red[(af * 16 + l4 * 4 + r) * 48 + bf * 16 + l15], acc[af][bf][r]);
  __syncthreads();
  float* dst = accD + (size_t)bh * 64 * 48;
  for (int i = tid; i < 64 * 48; i += 256) atomicAdd(&dst[i], red[i]);
}

// ---------------- out[n,d] = (qp[n,:] . kptv[d,:]) / (qp[n,:] . ks + eps) ----------------
// kptv fragments loaded directly from fp32 accD (fixup kernel fused away).
// written in scrambled layout: outr[b, h*512 + n/8, (n%8)*48 + d]
__global__ __launch_bounds__(256, 2) void attn_out(
    const unsigned short* __restrict__ qkv,
    const float* __restrict__ accD,
    unsigned short* __restrict__ outr) {
  const int bh = blockIdx.x >> 4, tg = blockIdx.x & 15;
  const int b = bh >> 3, h = bh & 7;
  const int tid = threadIdx.x, w = tid >> 6, lane = tid & 63;
  const int l15 = lane & 15, l4 = lane >> 4;
  const int t0 = tg * 256 + w * 64;

  // B-fragments: row = d (0..47 = kptv, 48 = ks), col = kernel-feature index m.
  short8 bfr[2][4];
#pragma unroll
  for (int kk = 0; kk < 2; ++kk) {
#pragma unroll
    for (int nf = 0; nf < 4; ++nf) {
      int row = nf * 16 + l15;
      int c0 = kk * 32 + l4 * 8;
      short8 f;
      if (kk == 1 && l4 >= 2) {
#pragma unroll
        for (int e = 0; e < 8; ++e) f[e] = 0;
      } else {
        const float* p = accD + (size_t)bh * 3072 + row * 48 + c0;
        float4 v0 = *(const float4*)p;
        float4 v1 = *(const float4*)(p + 4);
        f[0] = (short)f2bf(v0.x); f[1] = (short)f2bf(v0.y);
        f[2] = (short)f2bf(v0.z); f[3] = (short)f2bf(v0.w);
        f[4] = (short)f2bf(v1.x); f[5] = (short)f2bf(v1.y);
        f[6] = (short)f2bf(v1.z); f[7] = (short)f2bf(v1.w);
      }
      bfr[kk][nf] = f;
    }
  }

  floatx4 zero = {0.f, 0.f, 0.f, 0.f};
  floatx4 acc[4][4];
#pragma unroll
  for (int i = 0; i < 4; ++i)
#pragma unroll
    for (int j = 0; j < 4; ++j) acc[i][j] = zero;

  const size_t rb = (size_t)b * 4096;
#pragma unroll
  for (int mf = 0; mf < 4; ++mf) {
#pragma unroll
    for (int kk = 0; kk < 2; ++kk) {
      int tt = t0 + mf * 16 + l15;
      short8 a = *(const short8*)&qkv[(rb + tt) * 1152 + h * 48 + kk * 32 + l4 * 8];
#pragma unroll
      for (int nf = 0; nf < 4; ++nf)
        acc[mf][nf] = MFMA(a, bfr[kk][nf], acc[mf][nf]);
    }
  }

#pragma unroll
  for (int mf = 0; mf < 4; ++mf) {
    float den[4];
#pragma unroll
    for (int r = 0; r < 4; ++r)
      den[r] = __shfl(acc[mf][3][r], lane & 48, 64) + 1e-8f;
#pragma unroll
    for (int nf = 0; nf < 3; ++nf) {
#pragma unroll
      for (int r = 0; r < 4; ++r) {
        int tt = t0 + mf * 16 + l4 * 4 + r;
        int d = nf * 16 + l15;
        float v = acc[mf][nf][r] / den[r];
        int np = h * 512 + (tt >> 3);
        int cp = (tt & 7) * 48 + d;
        outr[(rb + np) * 384 + cp] = f2bf(v);
      }
    }
  }
}

extern "C" void kernel_launch(void* const* d_in, const int* in_sizes, int n_in,
                              void* d_out, int out_size, void* d_ws, size_t ws_size,
                              hipStream_t stream) {
  const float* x = (const float*)d_in[0];
  const float* Wqkv = (const float*)d_in[1];
  const float* Wproj = (const float*)d_in[2];
  const float* bproj = (const float*)d_in[3];

  char* ws = (char*)d_ws;
  unsigned short* xb = (unsigned short*)(ws);                 // 32768*384*2      = 25165824
  unsigned short* wqkvb = (unsigned short*)(ws + 25165824);   // 1152*384*2       = 884736
  unsigned short* wprojb = (unsigned short*)(ws + 26050560);  // 384*384*2        = 294912
  unsigned short* qkvA = (unsigned short*)(ws + 26345472);    // 32768*1152*2     = 75497472
  float* accD = (float*)(ws + 101842944);                     // 64*64*48*4       = 786432
  unsigned short* outr = (unsigned short*)(ws + 102629376);   // 32768*384*2      = 25165824
  // total ws use: 127795200 bytes

  conv_all<<<2048, 256, 0, stream>>>(x, Wqkv, Wproj, xb, wqkvb, wprojb, accD);
  gemm_bt<0><<<2304, 256, 0, stream>>>(xb, wqkvb, (void*)qkvA, nullptr, 32768, 1152, 384, 1152);
  attn_ksum<<<512, 256, 0, stream>>>(qkvA, accD);
  attn_out<<<1024, 256, 0, stream>>>(qkvA, accD, outr);
  gemm_bt<1><<<768, 256, 0, stream>>>(outr, wprojb, d_out, bproj, 32768, 384, 384, 384);
}